// Round 1
// baseline (3363.231 us; speedup 1.0000x reference)
//
#include <hip/hip_runtime.h>
#include <cmath>

namespace {

constexpr int BATCH = 64;
constexpr int NREG  = 49;
constexpr int FEATN = 2048;
constexpr int FHN   = 512;
constexpr int HID   = 512;
constexpr int EMBN  = 512;
constexpr int VOC   = 32000;
constexpr int TSTEPS= 40;
constexpr int G4    = 2048;   // 4*H
constexpr int NVT   = VOC / 128;  // 250 v-tiles for logits

__device__ __forceinline__ float sigm(float x) { return 1.0f / (1.0f + expf(-x)); }

// ---------------- feature embedding: femb[3136,512] = tanh(img @ W_fh + b) ----------------
__global__ __launch_bounds__(256) void k_feat(const float* __restrict__ img, const float* __restrict__ W,
                                              const float* __restrict__ bias, float* __restrict__ femb) {
  const int m0 = blockIdx.x * 64, n0 = blockIdx.y * 64;
  __shared__ float As[16][68];
  __shared__ float Bs[16][68];
  const int tid = threadIdx.x, tx = tid & 15, ty = tid >> 4;
  float acc[4][4] = {};
  for (int k0 = 0; k0 < FEATN; k0 += 16) {
#pragma unroll
    for (int e = 0; e < 4; ++e) {
      int idx = tid + e * 256, m = idx >> 4, k = idx & 15;
      As[k][m] = img[(size_t)(m0 + m) * FEATN + k0 + k];
    }
#pragma unroll
    for (int e = 0; e < 4; ++e) {
      int idx = tid + e * 256, k = idx >> 6, n = idx & 63;
      Bs[k][n] = W[(size_t)(k0 + k) * FHN + n0 + n];
    }
    __syncthreads();
#pragma unroll
    for (int k = 0; k < 16; ++k) {
      float4 av = *(const float4*)&As[k][ty * 4];
      float4 bv = *(const float4*)&Bs[k][tx * 4];
      float a[4] = {av.x, av.y, av.z, av.w}, b[4] = {bv.x, bv.y, bv.z, bv.w};
#pragma unroll
      for (int i = 0; i < 4; ++i)
#pragma unroll
        for (int j = 0; j < 4; ++j) acc[i][j] = fmaf(a[i], b[j], acc[i][j]);
    }
    __syncthreads();
  }
#pragma unroll
  for (int i = 0; i < 4; ++i) {
    int m = m0 + ty * 4 + i, n = n0 + tx * 4;
    float4 o;
    o.x = tanhf(acc[i][0] + bias[n + 0]);
    o.y = tanhf(acc[i][1] + bias[n + 1]);
    o.z = tanhf(acc[i][2] + bias[n + 2]);
    o.w = tanhf(acc[i][3] + bias[n + 3]);
    *(float4*)&femb[(size_t)m * FHN + n] = o;
  }
}

// ---------------- mean over regions: fmean[64,512] ----------------
__global__ void k_mean(const float* __restrict__ femb, float* __restrict__ fmean) {
  const int gid = blockIdx.x * 256 + threadIdx.x;  // 32768
  const int b = gid >> 9, f = gid & 511;
  float s = 0.f;
  for (int n = 0; n < NREG; ++n) s += femb[(size_t)(b * NREG + n) * FHN + f];
  fmean[gid] = s * (1.0f / NREG);
}

// ---------------- h0/c0 = fmean @ W{h,c}[l] + b{h,c}[l] ----------------
__global__ __launch_bounds__(256) void k_h0c0(const float* __restrict__ fmean,
    const float* __restrict__ Wc, const float* __restrict__ bc,
    const float* __restrict__ Wh, const float* __restrict__ bh,
    float* __restrict__ hbuf, float* __restrict__ cbuf) {
  const int n0 = blockIdx.x * 64, l = blockIdx.y, isH = blockIdx.z;
  const float* W   = (isH ? Wh : Wc) + (size_t)l * FHN * HID;
  const float* bias= (isH ? bh : bc) + l * HID;
  float* outp      = (isH ? hbuf : cbuf) + (size_t)l * BATCH * HID;
  __shared__ float As[16][68], Bs[16][68];
  const int tid = threadIdx.x, tx = tid & 15, ty = tid >> 4;
  float acc[4][4] = {};
  for (int k0 = 0; k0 < FHN; k0 += 16) {
#pragma unroll
    for (int e = 0; e < 4; ++e) { int idx = tid + e * 256, m = idx >> 4, k = idx & 15; As[k][m] = fmean[m * FHN + k0 + k]; }
#pragma unroll
    for (int e = 0; e < 4; ++e) { int idx = tid + e * 256, k = idx >> 6, n = idx & 63; Bs[k][n] = W[(size_t)(k0 + k) * HID + n0 + n]; }
    __syncthreads();
#pragma unroll
    for (int k = 0; k < 16; ++k) {
      float4 av = *(const float4*)&As[k][ty * 4];
      float4 bv = *(const float4*)&Bs[k][tx * 4];
      float a[4] = {av.x, av.y, av.z, av.w}, b[4] = {bv.x, bv.y, bv.z, bv.w};
#pragma unroll
      for (int i = 0; i < 4; ++i)
#pragma unroll
        for (int j = 0; j < 4; ++j) acc[i][j] = fmaf(a[i], b[j], acc[i][j]);
    }
    __syncthreads();
  }
#pragma unroll
  for (int i = 0; i < 4; ++i) {
    int m = ty * 4 + i, n = n0 + tx * 4;
    float4 o = make_float4(acc[i][0] + bias[n], acc[i][1] + bias[n + 1],
                           acc[i][2] + bias[n + 2], acc[i][3] + bias[n + 3]);
    *(float4*)&outp[(size_t)m * HID + n] = o;
  }
}

// ---------------- x0 = 3.0 ----------------
__global__ void k_init(float* __restrict__ xbuf) {
  xbuf[blockIdx.x * 256 + threadIdx.x] = 3.0f;
}

// ---------------- gates partial GEMM: part[ks][64][2048], split-K over (x@Wih | h@Whh) ----------------
__global__ __launch_bounds__(256) void k_gates(const float* __restrict__ X, const float* __restrict__ Hs,
    const float* __restrict__ Wih, const float* __restrict__ Whh, float* __restrict__ part) {
  const int n0 = blockIdx.x * 64;
  const int ks = blockIdx.y;        // 0..7 : 0-3 -> X/Wih, 4-7 -> H/Whh, 128 k each
  const float* A; const float* Wm; int kbase;
  if (ks < 4) { A = X;  Wm = Wih; kbase = ks * 128; }
  else        { A = Hs; Wm = Whh; kbase = (ks - 4) * 128; }
  __shared__ float As[16][68], Bs[16][68];
  const int tid = threadIdx.x, tx = tid & 15, ty = tid >> 4;
  float acc[4][4] = {};
  for (int kk = 0; kk < 128; kk += 16) {
    const int k0 = kbase + kk;
#pragma unroll
    for (int e = 0; e < 4; ++e) { int idx = tid + e * 256, m = idx >> 4, k = idx & 15; As[k][m] = A[m * EMBN + k0 + k]; }
#pragma unroll
    for (int e = 0; e < 4; ++e) { int idx = tid + e * 256, k = idx >> 6, n = idx & 63; Bs[k][n] = Wm[(size_t)(k0 + k) * G4 + n0 + n]; }
    __syncthreads();
#pragma unroll
    for (int k = 0; k < 16; ++k) {
      float4 av = *(const float4*)&As[k][ty * 4];
      float4 bvv = *(const float4*)&Bs[k][tx * 4];
      float a[4] = {av.x, av.y, av.z, av.w}, b[4] = {bvv.x, bvv.y, bvv.z, bvv.w};
#pragma unroll
      for (int i = 0; i < 4; ++i)
#pragma unroll
        for (int j = 0; j < 4; ++j) acc[i][j] = fmaf(a[i], b[j], acc[i][j]);
    }
    __syncthreads();
  }
  float* pp = part + (size_t)ks * BATCH * G4;
#pragma unroll
  for (int i = 0; i < 4; ++i) {
    int m = ty * 4 + i, n = n0 + tx * 4;
    *(float4*)&pp[(size_t)m * G4 + n] = make_float4(acc[i][0], acc[i][1], acc[i][2], acc[i][3]);
  }
}

// ---------------- LSTM cell: combine 8 partials + bias, update h,c ----------------
__global__ void k_cell(const float* __restrict__ part, const float* __restrict__ bias,
                       float* __restrict__ h, float* __restrict__ c) {
  const int gid = blockIdx.x * 256 + threadIdx.x;  // 32768
  const int b = gid >> 9, j = gid & 511;
  float gi = bias[j], gf = bias[j + 512], gg = bias[j + 1024], go = bias[j + 1536];
#pragma unroll
  for (int ks = 0; ks < 8; ++ks) {
    const float* p = part + (size_t)ks * BATCH * G4 + (size_t)b * G4;
    gi += p[j]; gf += p[j + 512]; gg += p[j + 1024]; go += p[j + 1536];
  }
  float cn = sigm(gf) * c[gid] + sigm(gi) * tanhf(gg);
  float hn = sigm(go) * tanhf(cn);
  c[gid] = cn; h[gid] = hn;
}

// ---------------- logits tile + per-block online LSE + gumbel-argmax partials ----------------
__global__ __launch_bounds__(256) void k_logits(const float* __restrict__ emb, const float* __restrict__ h1,
    const float* __restrict__ gum, float4* __restrict__ red) {
  const int v0 = blockIdx.x * 128;
  __shared__ float As[16][132];   // emb tile [k][v], 528B rows (16B aligned)
  __shared__ float Bs[16][68];    // h1 tile [k][b]
  __shared__ float Cs[128][65];   // logits tile [v][b]
  __shared__ float pm[4][64], ps[4][64], pv[4][64];
  __shared__ int   pi[4][64];
  const int tid = threadIdx.x, tx = tid & 15, ty = tid >> 4;
  float acc[8][4] = {};
  for (int k0 = 0; k0 < EMBN; k0 += 16) {
#pragma unroll
    for (int e = 0; e < 8; ++e) { int idx = tid + e * 256, v = idx >> 4, k = idx & 15; As[k][v] = emb[(size_t)(v0 + v) * EMBN + k0 + k]; }
#pragma unroll
    for (int e = 0; e < 4; ++e) { int idx = tid + e * 256, b = idx >> 4, k = idx & 15; Bs[k][b] = h1[b * EMBN + k0 + k]; }
    __syncthreads();
#pragma unroll
    for (int k = 0; k < 16; ++k) {
      float4 a0 = *(const float4*)&As[k][ty * 8];
      float4 a1 = *(const float4*)&As[k][ty * 8 + 4];
      float4 bv = *(const float4*)&Bs[k][tx * 4];
      float a[8] = {a0.x, a0.y, a0.z, a0.w, a1.x, a1.y, a1.z, a1.w};
      float b[4] = {bv.x, bv.y, bv.z, bv.w};
#pragma unroll
      for (int i = 0; i < 8; ++i)
#pragma unroll
        for (int j = 0; j < 4; ++j) acc[i][j] = fmaf(a[i], b[j], acc[i][j]);
    }
    __syncthreads();
  }
#pragma unroll
  for (int i = 0; i < 8; ++i)
#pragma unroll
    for (int j = 0; j < 4; ++j) Cs[ty * 8 + i][tx * 4 + j] = acc[i][j];
  __syncthreads();
  // per-(b, quarter) partial reduce over 32 v
  const int b = tid & 63, q = tid >> 6;
  float m = -INFINITY;
  for (int v = q * 32; v < q * 32 + 32; ++v) m = fmaxf(m, Cs[v][b]);
  float s = 0.f, bvv = -INFINITY; int bi = 0;
  const float* gb = gum + (size_t)b * VOC + v0;
  for (int v = q * 32; v < q * 32 + 32; ++v) {
    float lg = Cs[v][b];
    s += expf(lg - m);
    float val = lg + gb[v];
    if (val > bvv) { bvv = val; bi = v0 + v; }   // strict > keeps lowest index (jnp.argmax semantics)
  }
  pm[q][b] = m; ps[q][b] = s; pv[q][b] = bvv; pi[q][b] = bi;
  __syncthreads();
  if (tid < 64) {
    float M = pm[0][tid], S = ps[0][tid], BV = pv[0][tid]; int BI = pi[0][tid];
#pragma unroll
    for (int qq = 1; qq < 4; ++qq) {
      float m2 = pm[qq][tid], s2 = ps[qq][tid];
      float mm = fmaxf(M, m2);
      S = S * expf(M - mm) + s2 * expf(m2 - mm);
      M = mm;
      if (pv[qq][tid] > BV) { BV = pv[qq][tid]; BI = pi[qq][tid]; }
    }
    red[(size_t)blockIdx.x * 64 + tid] = make_float4(M, S, BV, (float)BI);
  }
}

// ---------------- final reduce + sample + lp + next embedding ----------------
__global__ __launch_bounds__(256) void k_sample(const float4* __restrict__ red, const float* __restrict__ emb,
    const float* __restrict__ h1, float* __restrict__ xnext, float* __restrict__ out, int t) {
  const int b = blockIdx.x, tid = threadIdx.x;
  __shared__ float rm[256], rs[256], rv[256];
  __shared__ int   ri[256];
  float m = -INFINITY, s = 0.f, bv = -INFINITY; int bi = 0x7fffffff;
  if (tid < NVT) {
    float4 r = red[(size_t)tid * 64 + b];
    m = r.x; s = r.y; bv = r.z; bi = (int)r.w;
  }
  rm[tid] = m; rs[tid] = s; rv[tid] = bv; ri[tid] = bi;
  __syncthreads();
  for (int off = 128; off > 0; off >>= 1) {
    if (tid < off) {
      float m1 = rm[tid], m2 = rm[tid + off], s1 = rs[tid], s2 = rs[tid + off];
      float mm = fmaxf(m1, m2);
      float ss = 0.f;
      if (m1 > -INFINITY) ss += s1 * expf(m1 - mm);
      if (m2 > -INFINITY) ss += s2 * expf(m2 - mm);
      rm[tid] = mm; rs[tid] = ss;
      float v2 = rv[tid + off]; int i2 = ri[tid + off];
      if (v2 > rv[tid] || (v2 == rv[tid] && i2 < ri[tid])) { rv[tid] = v2; ri[tid] = i2; }
    }
    __syncthreads();
  }
  const int tok = ri[0];
  const float lse = rm[0] + logf(rs[0]);
  __shared__ float sdot[256];
  float d = 0.f;
#pragma unroll
  for (int k = tid; k < EMBN; k += 256) {
    float ev = emb[(size_t)tok * EMBN + k];
    d = fmaf(ev, h1[b * EMBN + k], d);
    xnext[b * EMBN + k] = ev;
  }
  sdot[tid] = d;
  __syncthreads();
  for (int off = 128; off > 0; off >>= 1) {
    if (tid < off) sdot[tid] += sdot[tid + off];
    __syncthreads();
  }
  if (tid == 0) {
    out[b * TSTEPS + t] = (float)tok;                       // tokens.T [B,T]
    out[BATCH * TSTEPS + b * TSTEPS + t] = sdot[0] - lse;   // log_probs.T [B,T]
  }
}

}  // namespace

extern "C" void kernel_launch(void* const* d_in, const int* in_sizes, int n_in,
                              void* d_out, int out_size, void* d_ws, size_t ws_size,
                              hipStream_t stream) {
  const float* img  = (const float*)d_in[0];
  const float* W_fh = (const float*)d_in[1];
  const float* b_fh = (const float*)d_in[2];
  const float* Wc   = (const float*)d_in[3];
  const float* bc   = (const float*)d_in[4];
  const float* Wh   = (const float*)d_in[5];
  const float* bh   = (const float*)d_in[6];
  const float* W_ih = (const float*)d_in[7];
  const float* W_hh = (const float*)d_in[8];
  const float* b_l  = (const float*)d_in[9];
  const float* emb  = (const float*)d_in[10];
  const float* gum  = (const float*)d_in[11];
  float* out = (float*)d_out;

  float* w     = (float*)d_ws;
  float* femb  = w;                                   // 3136*512
  float* fmean = femb + (size_t)3136 * 512;           // 64*512
  float* hbuf  = fmean + 64 * 512;                    // 2*64*512
  float* cbuf  = hbuf + 2 * 64 * 512;                 // 2*64*512
  float* xbuf  = cbuf + 2 * 64 * 512;                 // 64*512
  float* part  = xbuf + 64 * 512;                     // 8*64*2048
  float4* red  = (float4*)(part + (size_t)8 * 64 * 2048);  // 250*64 float4

  k_feat<<<dim3(49, 8), 256, 0, stream>>>(img, W_fh, b_fh, femb);
  k_mean<<<128, 256, 0, stream>>>(femb, fmean);
  k_h0c0<<<dim3(8, 2, 2), 256, 0, stream>>>(fmean, Wc, bc, Wh, bh, hbuf, cbuf);
  k_init<<<128, 256, 0, stream>>>(xbuf);

  for (int t = 0; t < TSTEPS; ++t) {
    // layer 0
    k_gates<<<dim3(32, 8), 256, 0, stream>>>(xbuf, hbuf, W_ih, W_hh, part);
    k_cell<<<128, 256, 0, stream>>>(part, b_l, hbuf, cbuf);
    // layer 1 (input = new h of layer 0)
    k_gates<<<dim3(32, 8), 256, 0, stream>>>(hbuf, hbuf + 64 * 512,
                                             W_ih + (size_t)512 * 2048, W_hh + (size_t)512 * 2048, part);
    k_cell<<<128, 256, 0, stream>>>(part, b_l + 2048, hbuf + 64 * 512, cbuf + 64 * 512);
    // vocab projection + log-softmax partials + gumbel argmax
    k_logits<<<NVT, 256, 0, stream>>>(emb, hbuf + 64 * 512, gum + (size_t)t * 64 * 32000, red);
    k_sample<<<64, 256, 0, stream>>>(red, emb, hbuf + 64 * 512, xbuf, out, t);
  }
}

// Round 2
// 2216.154 us; speedup vs baseline: 1.5176x; 1.5176x over previous
//
#include <hip/hip_runtime.h>
#include <cmath>

namespace {

constexpr int BATCH = 64;
constexpr int NREG  = 49;
constexpr int FEATN = 2048;
constexpr int FHN   = 512;
constexpr int HID   = 512;
constexpr int EMBN  = 512;
constexpr int VOC   = 32000;
constexpr int TSTEPS= 40;
constexpr int G4    = 2048;       // 4*H
constexpr int NVT   = VOC / 128;  // 250 v-tiles for logits

typedef short bf16x8 __attribute__((ext_vector_type(8)));
typedef float f32x4  __attribute__((ext_vector_type(4)));

__device__ __forceinline__ float sigm(float x) { return 1.0f / (1.0f + expf(-x)); }

__device__ __forceinline__ unsigned short f2bf(float f) {
  unsigned u = __float_as_uint(f);
  unsigned r = (u + 0x7fffu + ((u >> 16) & 1u)) >> 16;   // RNE
  return (unsigned short)r;
}

__device__ __forceinline__ bool better(float a, int ia, float b, int ib) {
  return a > b || (a == b && ia < ib);
}
// merge sorted pair (u1,j1)>=(u2,j2) into sorted (v1,i1)>=(v2,i2)
__device__ __forceinline__ void top2_merge(float& v1, int& i1, float& v2, int& i2,
                                           float u1, int j1, float u2, int j2) {
  if (better(u1, j1, v1, i1)) {
    float t = v1; int ti = i1;
    v1 = u1; i1 = j1;
    if (better(u2, j2, t, ti)) { v2 = u2; i2 = j2; } else { v2 = t; i2 = ti; }
  } else {
    if (better(u1, j1, v2, i2)) { v2 = u1; i2 = j1; }
  }
}
__device__ __forceinline__ void lse_merge(float& m, float& s, float om, float os) {
  float nm = fmaxf(m, om);
  float ns = 0.f;
  if (m  > -INFINITY) ns += s  * expf(m  - nm);
  if (om > -INFINITY) ns += os * expf(om - nm);
  m = nm; s = ns;
}

// ---------------- feature embedding: femb[3136,512] = tanh(img @ W_fh + b) ----------------
__global__ __launch_bounds__(256) void k_feat(const float* __restrict__ img, const float* __restrict__ W,
                                              const float* __restrict__ bias, float* __restrict__ femb) {
  const int m0 = blockIdx.x * 64, n0 = blockIdx.y * 64;
  __shared__ float As[16][68];
  __shared__ float Bs[16][68];
  const int tid = threadIdx.x, tx = tid & 15, ty = tid >> 4;
  float acc[4][4] = {};
  for (int k0 = 0; k0 < FEATN; k0 += 16) {
#pragma unroll
    for (int e = 0; e < 4; ++e) {
      int idx = tid + e * 256, m = idx >> 4, k = idx & 15;
      As[k][m] = img[(size_t)(m0 + m) * FEATN + k0 + k];
    }
#pragma unroll
    for (int e = 0; e < 4; ++e) {
      int idx = tid + e * 256, k = idx >> 6, n = idx & 63;
      Bs[k][n] = W[(size_t)(k0 + k) * FHN + n0 + n];
    }
    __syncthreads();
#pragma unroll
    for (int k = 0; k < 16; ++k) {
      float4 av = *(const float4*)&As[k][ty * 4];
      float4 bv = *(const float4*)&Bs[k][tx * 4];
      float a[4] = {av.x, av.y, av.z, av.w}, b[4] = {bv.x, bv.y, bv.z, bv.w};
#pragma unroll
      for (int i = 0; i < 4; ++i)
#pragma unroll
        for (int j = 0; j < 4; ++j) acc[i][j] = fmaf(a[i], b[j], acc[i][j]);
    }
    __syncthreads();
  }
#pragma unroll
  for (int i = 0; i < 4; ++i) {
    int m = m0 + ty * 4 + i, n = n0 + tx * 4;
    float4 o;
    o.x = tanhf(acc[i][0] + bias[n + 0]);
    o.y = tanhf(acc[i][1] + bias[n + 1]);
    o.z = tanhf(acc[i][2] + bias[n + 2]);
    o.w = tanhf(acc[i][3] + bias[n + 3]);
    *(float4*)&femb[(size_t)m * FHN + n] = o;
  }
}

// ---------------- mean over regions ----------------
__global__ void k_mean(const float* __restrict__ femb, float* __restrict__ fmean) {
  const int gid = blockIdx.x * 256 + threadIdx.x;  // 32768
  const int b = gid >> 9, f = gid & 511;
  float s = 0.f;
  for (int n = 0; n < NREG; ++n) s += femb[(size_t)(b * NREG + n) * FHN + f];
  fmean[gid] = s * (1.0f / NREG);
}

// ---------------- h0/c0 ----------------
__global__ __launch_bounds__(256) void k_h0c0(const float* __restrict__ fmean,
    const float* __restrict__ Wc, const float* __restrict__ bc,
    const float* __restrict__ Wh, const float* __restrict__ bh,
    float* __restrict__ hbuf, float* __restrict__ cbuf) {
  const int n0 = blockIdx.x * 64, l = blockIdx.y, isH = blockIdx.z;
  const float* W   = (isH ? Wh : Wc) + (size_t)l * FHN * HID;
  const float* bias= (isH ? bh : bc) + l * HID;
  float* outp      = (isH ? hbuf : cbuf) + (size_t)l * BATCH * HID;
  __shared__ float As[16][68], Bs[16][68];
  const int tid = threadIdx.x, tx = tid & 15, ty = tid >> 4;
  float acc[4][4] = {};
  for (int k0 = 0; k0 < FHN; k0 += 16) {
#pragma unroll
    for (int e = 0; e < 4; ++e) { int idx = tid + e * 256, m = idx >> 4, k = idx & 15; As[k][m] = fmean[m * FHN + k0 + k]; }
#pragma unroll
    for (int e = 0; e < 4; ++e) { int idx = tid + e * 256, k = idx >> 6, n = idx & 63; Bs[k][n] = W[(size_t)(k0 + k) * HID + n0 + n]; }
    __syncthreads();
#pragma unroll
    for (int k = 0; k < 16; ++k) {
      float4 av = *(const float4*)&As[k][ty * 4];
      float4 bv = *(const float4*)&Bs[k][tx * 4];
      float a[4] = {av.x, av.y, av.z, av.w}, b[4] = {bv.x, bv.y, bv.z, bv.w};
#pragma unroll
      for (int i = 0; i < 4; ++i)
#pragma unroll
        for (int j = 0; j < 4; ++j) acc[i][j] = fmaf(a[i], b[j], acc[i][j]);
    }
    __syncthreads();
  }
#pragma unroll
  for (int i = 0; i < 4; ++i) {
    int m = ty * 4 + i, n = n0 + tx * 4;
    float4 o = make_float4(acc[i][0] + bias[n], acc[i][1] + bias[n + 1],
                           acc[i][2] + bias[n + 2], acc[i][3] + bias[n + 3]);
    *(float4*)&outp[(size_t)m * HID + n] = o;
  }
}

// ---------------- x0 = 3.0 ----------------
__global__ void k_init(float* __restrict__ xbuf) {
  xbuf[blockIdx.x * 256 + threadIdx.x] = 3.0f;
}

// ---------------- emb -> bf16 (once) ----------------
__global__ void k_emb2bf(const float* __restrict__ emb, unsigned short* __restrict__ ebf) {
  const int i = blockIdx.x * 256 + threadIdx.x;   // handles 8 elems
  const float4* p = reinterpret_cast<const float4*>(emb) + (size_t)i * 2;
  float4 a = p[0], b = p[1];
  uint4 o;
  o.x = (unsigned)f2bf(a.x) | ((unsigned)f2bf(a.y) << 16);
  o.y = (unsigned)f2bf(a.z) | ((unsigned)f2bf(a.w) << 16);
  o.z = (unsigned)f2bf(b.x) | ((unsigned)f2bf(b.y) << 16);
  o.w = (unsigned)f2bf(b.z) | ((unsigned)f2bf(b.w) << 16);
  reinterpret_cast<uint4*>(ebf)[i] = o;
}

// ---------------- gates partial GEMM (split-K=8) ----------------
__global__ __launch_bounds__(256) void k_gates(const float* __restrict__ X, const float* __restrict__ Hs,
    const float* __restrict__ Wih, const float* __restrict__ Whh, float* __restrict__ part) {
  const int n0 = blockIdx.x * 64;
  const int ks = blockIdx.y;        // 0-3 -> X/Wih, 4-7 -> H/Whh
  const float* A; const float* Wm; int kbase;
  if (ks < 4) { A = X;  Wm = Wih; kbase = ks * 128; }
  else        { A = Hs; Wm = Whh; kbase = (ks - 4) * 128; }
  __shared__ float As[16][68], Bs[16][68];
  const int tid = threadIdx.x, tx = tid & 15, ty = tid >> 4;
  float acc[4][4] = {};
  for (int kk = 0; kk < 128; kk += 16) {
    const int k0 = kbase + kk;
#pragma unroll
    for (int e = 0; e < 4; ++e) { int idx = tid + e * 256, m = idx >> 4, k = idx & 15; As[k][m] = A[m * EMBN + k0 + k]; }
#pragma unroll
    for (int e = 0; e < 4; ++e) { int idx = tid + e * 256, k = idx >> 6, n = idx & 63; Bs[k][n] = Wm[(size_t)(k0 + k) * G4 + n0 + n]; }
    __syncthreads();
#pragma unroll
    for (int k = 0; k < 16; ++k) {
      float4 av = *(const float4*)&As[k][ty * 4];
      float4 bvv = *(const float4*)&Bs[k][tx * 4];
      float a[4] = {av.x, av.y, av.z, av.w}, b[4] = {bvv.x, bvv.y, bvv.z, bvv.w};
#pragma unroll
      for (int i = 0; i < 4; ++i)
#pragma unroll
        for (int j = 0; j < 4; ++j) acc[i][j] = fmaf(a[i], b[j], acc[i][j]);
    }
    __syncthreads();
  }
  float* pp = part + (size_t)ks * BATCH * G4;
#pragma unroll
  for (int i = 0; i < 4; ++i) {
    int m = ty * 4 + i, n = n0 + tx * 4;
    *(float4*)&pp[(size_t)m * G4 + n] = make_float4(acc[i][0], acc[i][1], acc[i][2], acc[i][3]);
  }
}

// ---------------- LSTM cell (+ optional bf16 h emit) ----------------
__global__ void k_cell(const float* __restrict__ part, const float* __restrict__ bias,
                       float* __restrict__ h, float* __restrict__ c,
                       unsigned short* __restrict__ hbf) {
  const int gid = blockIdx.x * 256 + threadIdx.x;  // 32768
  const int b = gid >> 9, j = gid & 511;
  float gi = bias[j], gf = bias[j + 512], gg = bias[j + 1024], go = bias[j + 1536];
#pragma unroll
  for (int ks = 0; ks < 8; ++ks) {
    const float* p = part + (size_t)ks * BATCH * G4 + (size_t)b * G4;
    gi += p[j]; gf += p[j + 512]; gg += p[j + 1024]; go += p[j + 1536];
  }
  float cn = sigm(gf) * c[gid] + sigm(gi) * tanhf(gg);
  float hn = sigm(go) * tanhf(cn);
  c[gid] = cn; h[gid] = hn;
  if (hbf) hbf[gid] = f2bf(hn);
}

// ---------------- MFMA logits + online-LSE + top-2 gumbel screening ----------------
// red[block][b][8] = {m, s, v1, bits(i1), v2, bits(i2), 0, 0}
__global__ __launch_bounds__(256) void k_logits_mfma(
    const unsigned short* __restrict__ embbf,   // [32000][512] bf16
    const unsigned short* __restrict__ h1bf,    // [64][512] bf16
    const float* __restrict__ gum,              // [64][32000] (step slice)
    float* __restrict__ red) {
  const int v0 = blockIdx.x * 128;
  const int tid = threadIdx.x;
  const int lane = tid & 63, w = tid >> 6;
  const int l15 = lane & 15, l4 = lane >> 4;

  __shared__ unsigned short hl[32768];          // 64KB, [64][512] bf16, XOR-swizzled rows
  __shared__ float rm_[256], rs_[256], rv1_[256], rv2_[256];
  __shared__ int   ri1_[256], ri2_[256];

  // stage h1bf -> LDS with byte ^= ((row&7)<<4) swizzle (16B chunks)
#pragma unroll
  for (int i = 0; i < 16; ++i) {
    int c = tid + i * 256;              // chunk of 16B; 4096 chunks
    int row = c >> 6;
    int inb = (c & 63) << 4;
    uint4 v = *reinterpret_cast<const uint4*>(h1bf + ((size_t)c << 3));
    int sw = inb ^ ((row & 7) << 4);
    *reinterpret_cast<uint4*>(reinterpret_cast<char*>(hl) + row * 1024 + sw) = v;
  }
  __syncthreads();

  f32x4 acc[2][4];
#pragma unroll
  for (int m = 0; m < 2; ++m)
#pragma unroll
    for (int n = 0; n < 4; ++n) acc[m][n] = (f32x4){0.f, 0.f, 0.f, 0.f};

  const unsigned short* aptr = embbf + (size_t)(v0 + w * 32 + l15) * 512 + l4 * 8;
#pragma unroll
  for (int ks = 0; ks < 16; ++ks) {
    bf16x8 a0 = *reinterpret_cast<const bf16x8*>(aptr + ks * 32);
    bf16x8 a1 = *reinterpret_cast<const bf16x8*>(aptr + 16 * 512 + ks * 32);
    bf16x8 bb[4];
#pragma unroll
    for (int n = 0; n < 4; ++n) {
      int row = n * 16 + l15;
      int inb = ks * 64 + l4 * 16;
      int sw = inb ^ ((row & 7) << 4);
      bb[n] = *reinterpret_cast<const bf16x8*>(reinterpret_cast<const char*>(hl) + row * 1024 + sw);
    }
#pragma unroll
    for (int n = 0; n < 4; ++n) {
      acc[0][n] = __builtin_amdgcn_mfma_f32_16x16x32_bf16(a0, bb[n], acc[0][n], 0, 0, 0);
      acc[1][n] = __builtin_amdgcn_mfma_f32_16x16x32_bf16(a1, bb[n], acc[1][n], 0, 0, 0);
    }
  }

  // epilogue: per n-tile (i.e. per owned b), reduce over this wave's 32 v's
  const int vb = v0 + w * 32 + l4 * 4;
#pragma unroll
  for (int n = 0; n < 4; ++n) {
    const int b = n * 16 + l15;
    const float* gb = gum + (size_t)b * VOC + vb;
    float4 g0 = *reinterpret_cast<const float4*>(gb);
    float4 g1 = *reinterpret_cast<const float4*>(gb + 16);
    float lg[8] = {acc[0][n][0], acc[0][n][1], acc[0][n][2], acc[0][n][3],
                   acc[1][n][0], acc[1][n][1], acc[1][n][2], acc[1][n][3]};
    float gv[8] = {g0.x, g0.y, g0.z, g0.w, g1.x, g1.y, g1.z, g1.w};
    float mx = lg[0];
#pragma unroll
    for (int i = 1; i < 8; ++i) mx = fmaxf(mx, lg[i]);
    float ss = 0.f;
    float v1 = -INFINITY, v2 = -INFINITY; int i1 = 0x7fffffff, i2 = 0x7fffffff;
#pragma unroll
    for (int i = 0; i < 8; ++i) {
      ss += expf(lg[i] - mx);
      float val = lg[i] + gv[i];
      int idx = vb + (i & 3) + ((i >> 2) << 4);
      if (better(val, idx, v1, i1)) { v2 = v1; i2 = i1; v1 = val; i1 = idx; }
      else if (better(val, idx, v2, i2)) { v2 = val; i2 = idx; }
    }
    // cross-lane: merge lanes sharing (l&15) across lane bits 4,5
#pragma unroll
    for (int mask = 16; mask <= 32; mask <<= 1) {
      float om = __shfl_xor(mx, mask);
      float os = __shfl_xor(ss, mask);
      float u1 = __shfl_xor(v1, mask); int j1 = __shfl_xor(i1, mask);
      float u2 = __shfl_xor(v2, mask); int j2 = __shfl_xor(i2, mask);
      lse_merge(mx, ss, om, os);
      top2_merge(v1, i1, v2, i2, u1, j1, u2, j2);
    }
    if (lane < 16) {
      int slot = (w * 4 + n) * 16 + l15;
      rm_[slot] = mx; rs_[slot] = ss;
      rv1_[slot] = v1; ri1_[slot] = i1; rv2_[slot] = v2; ri2_[slot] = i2;
    }
  }
  __syncthreads();
  if (tid < 64) {
    const int n = tid >> 4, c = tid & 15;
    int s0 = n * 16 + c;
    float M = rm_[s0], S = rs_[s0], V1 = rv1_[s0], V2 = rv2_[s0];
    int I1 = ri1_[s0], I2 = ri2_[s0];
#pragma unroll
    for (int ww = 1; ww < 4; ++ww) {
      int sl = (ww * 4 + n) * 16 + c;
      lse_merge(M, S, rm_[sl], rs_[sl]);
      top2_merge(V1, I1, V2, I2, rv1_[sl], ri1_[sl], rv2_[sl], ri2_[sl]);
    }
    float* rp = red + ((size_t)blockIdx.x * 64 + tid) * 8;
    rp[0] = M; rp[1] = S;
    rp[2] = V1; rp[3] = __int_as_float(I1);
    rp[4] = V2; rp[5] = __int_as_float(I2);
  }
}

// ---------------- final reduce + exact f32 rescore + sample ----------------
__global__ __launch_bounds__(256) void k_sample(const float* __restrict__ red,
    const float* __restrict__ emb, const float* __restrict__ h1f, const float* __restrict__ gum,
    float* __restrict__ xnext, float* __restrict__ out, int t) {
  const int b = blockIdx.x, tid = threadIdx.x;
  __shared__ float rm[256], rs[256], rv1[256], rv2[256];
  __shared__ int   ri1[256], ri2[256];
  float m = -INFINITY, s = 0.f, v1 = -INFINITY, v2 = -INFINITY;
  int i1 = 0x7fffffff, i2 = 0x7fffffff;
  if (tid < NVT) {
    const float* rp = red + ((size_t)tid * 64 + b) * 8;
    m = rp[0]; s = rp[1];
    v1 = rp[2]; i1 = __float_as_int(rp[3]);
    v2 = rp[4]; i2 = __float_as_int(rp[5]);
  }
  rm[tid] = m; rs[tid] = s; rv1[tid] = v1; ri1[tid] = i1; rv2[tid] = v2; ri2[tid] = i2;
  __syncthreads();
  for (int off = 128; off > 0; off >>= 1) {
    if (tid < off) {
      float M = rm[tid], S = rs[tid];
      lse_merge(M, S, rm[tid + off], rs[tid + off]);
      rm[tid] = M; rs[tid] = S;
      float a1 = rv1[tid], a2 = rv2[tid]; int c1 = ri1[tid], c2 = ri2[tid];
      top2_merge(a1, c1, a2, c2, rv1[tid + off], ri1[tid + off], rv2[tid + off], ri2[tid + off]);
      rv1[tid] = a1; ri1[tid] = c1; rv2[tid] = a2; ri2[tid] = c2;
    }
    __syncthreads();
  }
  const int I1 = ri1[0], I2 = ri2[0];
  const float lse = rm[0] + logf(rs[0]);
  // exact f32 rescore of both candidates
  __shared__ float s1[256], s2[256];
  const float* e1 = emb + (size_t)I1 * EMBN;
  const float* e2 = emb + (size_t)I2 * EMBN;
  const float* hb = h1f + b * EMBN;
  float d1 = 0.f, d2 = 0.f;
  for (int k = tid; k < EMBN; k += 256) {
    float hv = hb[k];
    d1 = fmaf(e1[k], hv, d1);
    d2 = fmaf(e2[k], hv, d2);
  }
  s1[tid] = d1; s2[tid] = d2;
  __syncthreads();
  for (int off = 128; off > 0; off >>= 1) {
    if (tid < off) { s1[tid] += s1[tid + off]; s2[tid] += s2[tid + off]; }
    __syncthreads();
  }
  const float x1 = s1[0] + gum[(size_t)b * VOC + I1];
  const float x2 = s2[0] + gum[(size_t)b * VOC + I2];
  int tok; float dsel;
  if (x2 > x1 || (x2 == x1 && I2 < I1)) { tok = I2; dsel = s2[0]; }
  else                                  { tok = I1; dsel = s1[0]; }
  const float* et = emb + (size_t)tok * EMBN;
  for (int k = tid; k < EMBN; k += 256) xnext[b * EMBN + k] = et[k];
  if (tid == 0) {
    out[b * TSTEPS + t] = (float)tok;
    out[BATCH * TSTEPS + b * TSTEPS + t] = dsel - lse;
  }
}

}  // namespace

extern "C" void kernel_launch(void* const* d_in, const int* in_sizes, int n_in,
                              void* d_out, int out_size, void* d_ws, size_t ws_size,
                              hipStream_t stream) {
  const float* img  = (const float*)d_in[0];
  const float* W_fh = (const float*)d_in[1];
  const float* b_fh = (const float*)d_in[2];
  const float* Wc   = (const float*)d_in[3];
  const float* bc   = (const float*)d_in[4];
  const float* Wh   = (const float*)d_in[5];
  const float* bh   = (const float*)d_in[6];
  const float* W_ih = (const float*)d_in[7];
  const float* W_hh = (const float*)d_in[8];
  const float* b_l  = (const float*)d_in[9];
  const float* emb  = (const float*)d_in[10];
  const float* gum  = (const float*)d_in[11];
  float* out = (float*)d_out;

  float* w     = (float*)d_ws;
  float* femb  = w;                                    // 3136*512
  float* fmean = femb + (size_t)3136 * 512;            // 64*512
  float* hbuf  = fmean + 64 * 512;                     // 2*64*512
  float* cbuf  = hbuf + 2 * 64 * 512;                  // 2*64*512
  float* xbuf  = cbuf + 2 * 64 * 512;                  // 64*512
  float* part  = xbuf + 64 * 512;                      // 8*64*2048
  float* red   = part + (size_t)8 * 64 * 2048;         // 250*64*8
  unsigned short* embbf = (unsigned short*)(red + 250 * 64 * 8);  // 32000*512 bf16
  unsigned short* h1bf  = embbf + (size_t)VOC * EMBN;             // 64*512 bf16

  k_feat<<<dim3(49, 8), 256, 0, stream>>>(img, W_fh, b_fh, femb);
  k_mean<<<128, 256, 0, stream>>>(femb, fmean);
  k_h0c0<<<dim3(8, 2, 2), 256, 0, stream>>>(fmean, Wc, bc, Wh, bh, hbuf, cbuf);
  k_init<<<128, 256, 0, stream>>>(xbuf);
  k_emb2bf<<<8000, 256, 0, stream>>>(emb, embbf);

  for (int t = 0; t < TSTEPS; ++t) {
    const float* gum_t = gum + (size_t)t * BATCH * VOC;
    // layer 0
    k_gates<<<dim3(32, 8), 256, 0, stream>>>(xbuf, hbuf, W_ih, W_hh, part);
    k_cell<<<128, 256, 0, stream>>>(part, b_l, hbuf, cbuf, (unsigned short*)nullptr);
    // layer 1
    k_gates<<<dim3(32, 8), 256, 0, stream>>>(hbuf, hbuf + 64 * 512,
                                             W_ih + (size_t)512 * 2048, W_hh + (size_t)512 * 2048, part);
    k_cell<<<128, 256, 0, stream>>>(part, b_l + 2048, hbuf + 64 * 512, cbuf + 64 * 512, h1bf);
    // vocab projection (bf16 MFMA) + LSE partials + top-2 screening
    k_logits_mfma<<<NVT, 256, 0, stream>>>(embbf, h1bf, gum_t, red);
    // final reduce + exact rescore + sample
    k_sample<<<64, 256, 0, stream>>>(red, emb, hbuf + 64 * 512, gum_t, xbuf, out, t);
  }
}

// Round 3
// 2040.320 us; speedup vs baseline: 1.6484x; 1.0862x over previous
//
#include <hip/hip_runtime.h>
#include <cmath>

namespace {

constexpr int BATCH = 64;
constexpr int NREG  = 49;
constexpr int FEATN = 2048;
constexpr int FHN   = 512;
constexpr int HID   = 512;
constexpr int EMBN  = 512;
constexpr int VOC   = 32000;
constexpr int TSTEPS= 40;
constexpr int G4    = 2048;       // 4*H
constexpr int NVT   = VOC / 128;  // 250 v-tiles for logits

typedef short bf16x8 __attribute__((ext_vector_type(8)));
typedef float f32x4  __attribute__((ext_vector_type(4)));

__device__ __forceinline__ float sigm(float x) { return 1.0f / (1.0f + expf(-x)); }

__device__ __forceinline__ unsigned short f2bf(float f) {
  unsigned u = __float_as_uint(f);
  unsigned r = (u + 0x7fffu + ((u >> 16) & 1u)) >> 16;   // RNE
  return (unsigned short)r;
}
__device__ __forceinline__ float bf2f(unsigned short h) {
  return __uint_as_float(((unsigned)h) << 16);
}

__device__ __forceinline__ bool better(float a, int ia, float b, int ib) {
  return a > b || (a == b && ia < ib);
}
__device__ __forceinline__ void top2_merge(float& v1, int& i1, float& v2, int& i2,
                                           float u1, int j1, float u2, int j2) {
  if (better(u1, j1, v1, i1)) {
    float t = v1; int ti = i1;
    v1 = u1; i1 = j1;
    if (better(u2, j2, t, ti)) { v2 = u2; i2 = j2; } else { v2 = t; i2 = ti; }
  } else {
    if (better(u1, j1, v2, i2)) { v2 = u1; i2 = j1; }
  }
}
__device__ __forceinline__ void lse_merge(float& m, float& s, float om, float os) {
  float nm = fmaxf(m, om);
  float ns = 0.f;
  if (m  > -INFINITY) ns += s  * expf(m  - nm);
  if (om > -INFINITY) ns += os * expf(om - nm);
  m = nm; s = ns;
}

// ---------------- transpose + bf16 hi/lo split: src[K][N] f32 -> dhi/dlo[N][K] bf16 ----------------
__global__ __launch_bounds__(256) void k_trans(const float* __restrict__ src,
    unsigned short* __restrict__ dhi, unsigned short* __restrict__ dlo, int K, int N) {
  __shared__ float tile[32][33];
  const int k0 = blockIdx.x * 32, n0 = blockIdx.y * 32;
  const int tx = threadIdx.x & 31, ty = threadIdx.x >> 5;
#pragma unroll
  for (int r = ty; r < 32; r += 8) tile[r][tx] = src[(size_t)(k0 + r) * N + n0 + tx];
  __syncthreads();
#pragma unroll
  for (int r = ty; r < 32; r += 8) {
    float v = tile[tx][r];
    unsigned short hv = f2bf(v);
    size_t o = (size_t)(n0 + r) * K + k0 + tx;
    dhi[o] = hv;
    dlo[o] = f2bf(v - bf2f(hv));
  }
}

// ---------------- elementwise bf16 hi/lo split (8 elems/thread) ----------------
__global__ void k_split(const float* __restrict__ src, unsigned short* __restrict__ dhi,
                        unsigned short* __restrict__ dlo) {
  const size_t i = (size_t)blockIdx.x * 256 + threadIdx.x;
  const float4* p = reinterpret_cast<const float4*>(src) + i * 2;
  float4 a = p[0], b = p[1];
  float v[8] = {a.x, a.y, a.z, a.w, b.x, b.y, b.z, b.w};
  unsigned short hi[8], lo[8];
#pragma unroll
  for (int j = 0; j < 8; ++j) {
    hi[j] = f2bf(v[j]);
    lo[j] = f2bf(v[j] - bf2f(hi[j]));
  }
  uint4 oh, ol;
  oh.x = hi[0] | (hi[1] << 16); oh.y = hi[2] | (hi[3] << 16);
  oh.z = hi[4] | (hi[5] << 16); oh.w = hi[6] | (hi[7] << 16);
  ol.x = lo[0] | (lo[1] << 16); ol.y = lo[2] | (lo[3] << 16);
  ol.z = lo[4] | (lo[5] << 16); ol.w = lo[6] | (lo[7] << 16);
  reinterpret_cast<uint4*>(dhi)[i] = oh;
  reinterpret_cast<uint4*>(dlo)[i] = ol;
}

// ---------------- emb -> bf16 (once) ----------------
__global__ void k_emb2bf(const float* __restrict__ emb, unsigned short* __restrict__ ebf) {
  const size_t i = (size_t)blockIdx.x * 256 + threadIdx.x;
  const float4* p = reinterpret_cast<const float4*>(emb) + i * 2;
  float4 a = p[0], b = p[1];
  uint4 o;
  o.x = (unsigned)f2bf(a.x) | ((unsigned)f2bf(a.y) << 16);
  o.y = (unsigned)f2bf(a.z) | ((unsigned)f2bf(a.w) << 16);
  o.z = (unsigned)f2bf(b.x) | ((unsigned)f2bf(b.y) << 16);
  o.w = (unsigned)f2bf(b.z) | ((unsigned)f2bf(b.w) << 16);
  reinterpret_cast<uint4*>(ebf)[i] = o;
}

// ---------------- feature embedding via bf16x3 MFMA: femb = tanh(img @ W_fh + b) ----------------
__global__ __launch_bounds__(256) void k_feat_mfma(
    const unsigned short* __restrict__ Ahi, const unsigned short* __restrict__ Alo,  // [3136][2048]
    const unsigned short* __restrict__ Bhi, const unsigned short* __restrict__ Blo,  // [512][2048] (W^T)
    const float* __restrict__ bias, float* __restrict__ femb) {
  const int m0 = blockIdx.x * 64, n0 = blockIdx.y * 64;
  const int tid = threadIdx.x, lane = tid & 63, w = tid >> 6;
  const int l15 = lane & 15, l4 = lane >> 4;
  f32x4 acc[4];
#pragma unroll
  for (int nt = 0; nt < 4; ++nt) acc[nt] = (f32x4){0.f, 0.f, 0.f, 0.f};
  const size_t arow = (size_t)(m0 + w * 16 + l15) * FEATN;
  for (int kk = 0; kk < FEATN / 32; ++kk) {
    const int k = kk * 32 + l4 * 8;
    bf16x8 a1 = *reinterpret_cast<const bf16x8*>(Ahi + arow + k);
    bf16x8 a2 = *reinterpret_cast<const bf16x8*>(Alo + arow + k);
#pragma unroll
    for (int nt = 0; nt < 4; ++nt) {
      const size_t brow = (size_t)(n0 + nt * 16 + l15) * FEATN + k;
      bf16x8 b1 = *reinterpret_cast<const bf16x8*>(Bhi + brow);
      bf16x8 b2 = *reinterpret_cast<const bf16x8*>(Blo + brow);
      acc[nt] = __builtin_amdgcn_mfma_f32_16x16x32_bf16(a1, b1, acc[nt], 0, 0, 0);
      acc[nt] = __builtin_amdgcn_mfma_f32_16x16x32_bf16(a1, b2, acc[nt], 0, 0, 0);
      acc[nt] = __builtin_amdgcn_mfma_f32_16x16x32_bf16(a2, b1, acc[nt], 0, 0, 0);
    }
  }
#pragma unroll
  for (int nt = 0; nt < 4; ++nt)
#pragma unroll
    for (int i = 0; i < 4; ++i) {
      int m = m0 + w * 16 + l4 * 4 + i, n = n0 + nt * 16 + l15;
      femb[(size_t)m * FHN + n] = tanhf(acc[nt][i] + bias[n]);
    }
}

// ---------------- mean over regions ----------------
__global__ void k_mean(const float* __restrict__ femb, float* __restrict__ fmean) {
  const int gid = blockIdx.x * 256 + threadIdx.x;  // 32768
  const int b = gid >> 9, f = gid & 511;
  float s = 0.f;
  for (int n = 0; n < NREG; ++n) s += femb[(size_t)(b * NREG + n) * FHN + f];
  fmean[gid] = s * (1.0f / NREG);
}

// ---------------- h0/c0 (f32 GEMM, small) + h split emit ----------------
__global__ __launch_bounds__(256) void k_h0c0(const float* __restrict__ fmean,
    const float* __restrict__ Wc, const float* __restrict__ bc,
    const float* __restrict__ Wh, const float* __restrict__ bh,
    float* __restrict__ hbuf, float* __restrict__ cbuf,
    unsigned short* __restrict__ hshi, unsigned short* __restrict__ hslo) {
  const int n0 = blockIdx.x * 64, l = blockIdx.y, isH = blockIdx.z;
  const float* W   = (isH ? Wh : Wc) + (size_t)l * FHN * HID;
  const float* bias= (isH ? bh : bc) + l * HID;
  float* outp      = (isH ? hbuf : cbuf) + (size_t)l * BATCH * HID;
  __shared__ float As[16][68], Bs[16][68];
  const int tid = threadIdx.x, tx = tid & 15, ty = tid >> 4;
  float acc[4][4] = {};
  for (int k0 = 0; k0 < FHN; k0 += 16) {
#pragma unroll
    for (int e = 0; e < 4; ++e) { int idx = tid + e * 256, m = idx >> 4, k = idx & 15; As[k][m] = fmean[m * FHN + k0 + k]; }
#pragma unroll
    for (int e = 0; e < 4; ++e) { int idx = tid + e * 256, k = idx >> 6, n = idx & 63; Bs[k][n] = W[(size_t)(k0 + k) * HID + n0 + n]; }
    __syncthreads();
#pragma unroll
    for (int k = 0; k < 16; ++k) {
      float4 av = *(const float4*)&As[k][ty * 4];
      float4 bv = *(const float4*)&Bs[k][tx * 4];
      float a[4] = {av.x, av.y, av.z, av.w}, b[4] = {bv.x, bv.y, bv.z, bv.w};
#pragma unroll
      for (int i = 0; i < 4; ++i)
#pragma unroll
        for (int j = 0; j < 4; ++j) acc[i][j] = fmaf(a[i], b[j], acc[i][j]);
    }
    __syncthreads();
  }
#pragma unroll
  for (int i = 0; i < 4; ++i) {
    int m = ty * 4 + i, n = n0 + tx * 4;
    float vals[4];
#pragma unroll
    for (int j = 0; j < 4; ++j) vals[j] = acc[i][j] + bias[n + j];
    *(float4*)&outp[(size_t)m * HID + n] = make_float4(vals[0], vals[1], vals[2], vals[3]);
    if (isH) {
#pragma unroll
      for (int j = 0; j < 4; ++j) {
        unsigned short hv = f2bf(vals[j]);
        size_t o = (size_t)l * BATCH * HID + (size_t)m * HID + n + j;
        hshi[o] = hv;
        hslo[o] = f2bf(vals[j] - bf2f(hv));
      }
    }
  }
}

// ---------------- x0 = 3.0 (exact in bf16: hi=0x4040, lo=0) ----------------
__global__ void k_initx(unsigned short* __restrict__ xhi, unsigned short* __restrict__ xlo) {
  const int i = blockIdx.x * 256 + threadIdx.x;
  xhi[i] = 0x4040; xlo[i] = 0;
}

// ---------------- gates via bf16x3 MFMA, split-K=8, no LDS ----------------
__global__ __launch_bounds__(256) void k_gates_mfma(
    const unsigned short* __restrict__ xhi, const unsigned short* __restrict__ xlo,   // [64][512]
    const unsigned short* __restrict__ hhi, const unsigned short* __restrict__ hlo,   // [64][512]
    const unsigned short* __restrict__ wih_hi, const unsigned short* __restrict__ wih_lo,  // [2048][512] W^T
    const unsigned short* __restrict__ whh_hi, const unsigned short* __restrict__ whh_lo,
    float* __restrict__ part) {
  const int n0 = blockIdx.x * 64;
  const int ks = blockIdx.y;        // 0-3 -> x/Wih, 4-7 -> h/Whh
  const unsigned short *Ah, *Al, *Wh_, *Wl;
  int kbase;
  if (ks < 4) { Ah = xhi; Al = xlo; Wh_ = wih_hi; Wl = wih_lo; kbase = ks * 128; }
  else        { Ah = hhi; Al = hlo; Wh_ = whh_hi; Wl = whh_lo; kbase = (ks - 4) * 128; }
  const int tid = threadIdx.x, lane = tid & 63, w = tid >> 6;
  const int l15 = lane & 15, l4 = lane >> 4;
  f32x4 acc[4];
#pragma unroll
  for (int nt = 0; nt < 4; ++nt) acc[nt] = (f32x4){0.f, 0.f, 0.f, 0.f};
  const size_t arow = (size_t)(w * 16 + l15) * EMBN;
#pragma unroll
  for (int kk = 0; kk < 4; ++kk) {
    const int k = kbase + kk * 32 + l4 * 8;
    bf16x8 a1 = *reinterpret_cast<const bf16x8*>(Ah + arow + k);
    bf16x8 a2 = *reinterpret_cast<const bf16x8*>(Al + arow + k);
#pragma unroll
    for (int nt = 0; nt < 4; ++nt) {
      const size_t brow = (size_t)(n0 + nt * 16 + l15) * EMBN + k;
      bf16x8 b1 = *reinterpret_cast<const bf16x8*>(Wh_ + brow);
      bf16x8 b2 = *reinterpret_cast<const bf16x8*>(Wl + brow);
      acc[nt] = __builtin_amdgcn_mfma_f32_16x16x32_bf16(a1, b1, acc[nt], 0, 0, 0);
      acc[nt] = __builtin_amdgcn_mfma_f32_16x16x32_bf16(a1, b2, acc[nt], 0, 0, 0);
      acc[nt] = __builtin_amdgcn_mfma_f32_16x16x32_bf16(a2, b1, acc[nt], 0, 0, 0);
    }
  }
  float* pp = part + (size_t)ks * BATCH * G4;
#pragma unroll
  for (int nt = 0; nt < 4; ++nt)
#pragma unroll
    for (int i = 0; i < 4; ++i) {
      int b = w * 16 + l4 * 4 + i, n = n0 + nt * 16 + l15;
      pp[(size_t)b * G4 + n] = acc[nt][i];
    }
}

// ---------------- LSTM cell + h bf16 hi/lo emit ----------------
__global__ void k_cell(const float* __restrict__ part, const float* __restrict__ bias,
                       float* __restrict__ h, float* __restrict__ c,
                       unsigned short* __restrict__ hhi, unsigned short* __restrict__ hlo) {
  const int gid = blockIdx.x * 256 + threadIdx.x;  // 32768
  const int b = gid >> 9, j = gid & 511;
  float gi = bias[j], gf = bias[j + 512], gg = bias[j + 1024], go = bias[j + 1536];
#pragma unroll
  for (int ks = 0; ks < 8; ++ks) {
    const float* p = part + (size_t)ks * BATCH * G4 + (size_t)b * G4;
    gi += p[j]; gf += p[j + 512]; gg += p[j + 1024]; go += p[j + 1536];
  }
  float cn = sigm(gf) * c[gid] + sigm(gi) * tanhf(gg);
  float hn = sigm(go) * tanhf(cn);
  c[gid] = cn; h[gid] = hn;
  unsigned short hv = f2bf(hn);
  hhi[gid] = hv;
  hlo[gid] = f2bf(hn - bf2f(hv));
}

// ---------------- MFMA logits + online-LSE + top-2 gumbel screening ----------------
__global__ __launch_bounds__(256) void k_logits_mfma(
    const unsigned short* __restrict__ embbf,   // [32000][512] bf16
    const unsigned short* __restrict__ h1bf,    // [64][512] bf16 (hi split of h1)
    const float* __restrict__ gum,              // [64][32000] (step slice)
    float* __restrict__ red) {
  const int v0 = blockIdx.x * 128;
  const int tid = threadIdx.x;
  const int lane = tid & 63, w = tid >> 6;
  const int l15 = lane & 15, l4 = lane >> 4;

  __shared__ unsigned short hl[32768];          // 64KB, [64][512] bf16, XOR-swizzled rows
  __shared__ float rm_[256], rs_[256], rv1_[256], rv2_[256];
  __shared__ int   ri1_[256], ri2_[256];

#pragma unroll
  for (int i = 0; i < 16; ++i) {
    int c = tid + i * 256;
    int row = c >> 6;
    int inb = (c & 63) << 4;
    uint4 v = *reinterpret_cast<const uint4*>(h1bf + ((size_t)c << 3));
    int sw = inb ^ ((row & 7) << 4);
    *reinterpret_cast<uint4*>(reinterpret_cast<char*>(hl) + row * 1024 + sw) = v;
  }
  __syncthreads();

  f32x4 acc[2][4];
#pragma unroll
  for (int m = 0; m < 2; ++m)
#pragma unroll
    for (int n = 0; n < 4; ++n) acc[m][n] = (f32x4){0.f, 0.f, 0.f, 0.f};

  const unsigned short* aptr = embbf + (size_t)(v0 + w * 32 + l15) * 512 + l4 * 8;
#pragma unroll
  for (int ks = 0; ks < 16; ++ks) {
    bf16x8 a0 = *reinterpret_cast<const bf16x8*>(aptr + ks * 32);
    bf16x8 a1 = *reinterpret_cast<const bf16x8*>(aptr + 16 * 512 + ks * 32);
    bf16x8 bb[4];
#pragma unroll
    for (int n = 0; n < 4; ++n) {
      int row = n * 16 + l15;
      int inb = ks * 64 + l4 * 16;
      int sw = inb ^ ((row & 7) << 4);
      bb[n] = *reinterpret_cast<const bf16x8*>(reinterpret_cast<const char*>(hl) + row * 1024 + sw);
    }
#pragma unroll
    for (int n = 0; n < 4; ++n) {
      acc[0][n] = __builtin_amdgcn_mfma_f32_16x16x32_bf16(a0, bb[n], acc[0][n], 0, 0, 0);
      acc[1][n] = __builtin_amdgcn_mfma_f32_16x16x32_bf16(a1, bb[n], acc[1][n], 0, 0, 0);
    }
  }

  const int vb = v0 + w * 32 + l4 * 4;
#pragma unroll
  for (int n = 0; n < 4; ++n) {
    const int b = n * 16 + l15;
    const float* gb = gum + (size_t)b * VOC + vb;
    float4 g0 = *reinterpret_cast<const float4*>(gb);
    float4 g1 = *reinterpret_cast<const float4*>(gb + 16);
    float lg[8] = {acc[0][n][0], acc[0][n][1], acc[0][n][2], acc[0][n][3],
                   acc[1][n][0], acc[1][n][1], acc[1][n][2], acc[1][n][3]};
    float gv[8] = {g0.x, g0.y, g0.z, g0.w, g1.x, g1.y, g1.z, g1.w};
    float mx = lg[0];
#pragma unroll
    for (int i = 1; i < 8; ++i) mx = fmaxf(mx, lg[i]);
    float ss = 0.f;
    float v1 = -INFINITY, v2 = -INFINITY; int i1 = 0x7fffffff, i2 = 0x7fffffff;
#pragma unroll
    for (int i = 0; i < 8; ++i) {
      ss += expf(lg[i] - mx);
      float val = lg[i] + gv[i];
      int idx = vb + (i & 3) + ((i >> 2) << 4);
      if (better(val, idx, v1, i1)) { v2 = v1; i2 = i1; v1 = val; i1 = idx; }
      else if (better(val, idx, v2, i2)) { v2 = val; i2 = idx; }
    }
#pragma unroll
    for (int mask = 16; mask <= 32; mask <<= 1) {
      float om = __shfl_xor(mx, mask);
      float os = __shfl_xor(ss, mask);
      float u1 = __shfl_xor(v1, mask); int j1 = __shfl_xor(i1, mask);
      float u2 = __shfl_xor(v2, mask); int j2 = __shfl_xor(i2, mask);
      lse_merge(mx, ss, om, os);
      top2_merge(v1, i1, v2, i2, u1, j1, u2, j2);
    }
    if (lane < 16) {
      int slot = (w * 4 + n) * 16 + l15;
      rm_[slot] = mx; rs_[slot] = ss;
      rv1_[slot] = v1; ri1_[slot] = i1; rv2_[slot] = v2; ri2_[slot] = i2;
    }
  }
  __syncthreads();
  if (tid < 64) {
    const int n = tid >> 4, c = tid & 15;
    int s0 = n * 16 + c;
    float M = rm_[s0], S = rs_[s0], V1 = rv1_[s0], V2 = rv2_[s0];
    int I1 = ri1_[s0], I2 = ri2_[s0];
#pragma unroll
    for (int ww = 1; ww < 4; ++ww) {
      int sl = (ww * 4 + n) * 16 + c;
      lse_merge(M, S, rm_[sl], rs_[sl]);
      top2_merge(V1, I1, V2, I2, rv1_[sl], ri1_[sl], rv2_[sl], ri2_[sl]);
    }
    float* rp = red + ((size_t)blockIdx.x * 64 + tid) * 8;
    rp[0] = M; rp[1] = S;
    rp[2] = V1; rp[3] = __int_as_float(I1);
    rp[4] = V2; rp[5] = __int_as_float(I2);
  }
}

// ---------------- final reduce + exact f32 rescore + sample + x split emit ----------------
__global__ __launch_bounds__(256) void k_sample(const float* __restrict__ red,
    const float* __restrict__ emb, const float* __restrict__ h1f, const float* __restrict__ gum,
    unsigned short* __restrict__ xhi, unsigned short* __restrict__ xlo,
    float* __restrict__ out, int t) {
  const int b = blockIdx.x, tid = threadIdx.x;
  __shared__ float rm[256], rs[256], rv1[256], rv2[256];
  __shared__ int   ri1[256], ri2[256];
  float m = -INFINITY, s = 0.f, v1 = -INFINITY, v2 = -INFINITY;
  int i1 = 0x7fffffff, i2 = 0x7fffffff;
  if (tid < NVT) {
    const float* rp = red + ((size_t)tid * 64 + b) * 8;
    m = rp[0]; s = rp[1];
    v1 = rp[2]; i1 = __float_as_int(rp[3]);
    v2 = rp[4]; i2 = __float_as_int(rp[5]);
  }
  rm[tid] = m; rs[tid] = s; rv1[tid] = v1; ri1[tid] = i1; rv2[tid] = v2; ri2[tid] = i2;
  __syncthreads();
  for (int off = 128; off > 0; off >>= 1) {
    if (tid < off) {
      float M = rm[tid], S = rs[tid];
      lse_merge(M, S, rm[tid + off], rs[tid + off]);
      rm[tid] = M; rs[tid] = S;
      float a1 = rv1[tid], a2 = rv2[tid]; int c1 = ri1[tid], c2 = ri2[tid];
      top2_merge(a1, c1, a2, c2, rv1[tid + off], ri1[tid + off], rv2[tid + off], ri2[tid + off]);
      rv1[tid] = a1; ri1[tid] = c1; rv2[tid] = a2; ri2[tid] = c2;
    }
    __syncthreads();
  }
  const int I1 = ri1[0], I2 = ri2[0];
  const float lse = rm[0] + logf(rs[0]);
  __shared__ float s1[256], s2[256];
  const float* e1 = emb + (size_t)I1 * EMBN;
  const float* e2 = emb + (size_t)I2 * EMBN;
  const float* hb = h1f + b * EMBN;
  float d1 = 0.f, d2 = 0.f;
  for (int k = tid; k < EMBN; k += 256) {
    float hv = hb[k];
    d1 = fmaf(e1[k], hv, d1);
    d2 = fmaf(e2[k], hv, d2);
  }
  s1[tid] = d1; s2[tid] = d2;
  __syncthreads();
  for (int off = 128; off > 0; off >>= 1) {
    if (tid < off) { s1[tid] += s1[tid + off]; s2[tid] += s2[tid + off]; }
    __syncthreads();
  }
  const float x1 = s1[0] + gum[(size_t)b * VOC + I1];
  const float x2 = s2[0] + gum[(size_t)b * VOC + I2];
  int tok; float dsel;
  if (x2 > x1 || (x2 == x1 && I2 < I1)) { tok = I2; dsel = s2[0]; }
  else                                  { tok = I1; dsel = s1[0]; }
  const float* et = emb + (size_t)tok * EMBN;
  for (int k = tid; k < EMBN; k += 256) {
    float ev = et[k];
    unsigned short hv = f2bf(ev);
    xhi[b * EMBN + k] = hv;
    xlo[b * EMBN + k] = f2bf(ev - bf2f(hv));
  }
  if (tid == 0) {
    out[b * TSTEPS + t] = (float)tok;
    out[BATCH * TSTEPS + b * TSTEPS + t] = dsel - lse;
  }
}

}  // namespace

extern "C" void kernel_launch(void* const* d_in, const int* in_sizes, int n_in,
                              void* d_out, int out_size, void* d_ws, size_t ws_size,
                              hipStream_t stream) {
  const float* img  = (const float*)d_in[0];
  const float* W_fh = (const float*)d_in[1];
  const float* b_fh = (const float*)d_in[2];
  const float* Wc   = (const float*)d_in[3];
  const float* bc   = (const float*)d_in[4];
  const float* Wh   = (const float*)d_in[5];
  const float* bh   = (const float*)d_in[6];
  const float* W_ih = (const float*)d_in[7];
  const float* W_hh = (const float*)d_in[8];
  const float* b_l  = (const float*)d_in[9];
  const float* emb  = (const float*)d_in[10];
  const float* gum  = (const float*)d_in[11];
  float* out = (float*)d_out;

  float* w     = (float*)d_ws;
  float* femb  = w;                                    // 3136*512
  float* fmean = femb + (size_t)3136 * 512;            // 64*512
  float* hbuf  = fmean + 64 * 512;                     // 2*64*512
  float* cbuf  = hbuf + 2 * 64 * 512;                  // 2*64*512
  float* part  = cbuf + 2 * 64 * 512;                  // 8*64*2048
  float* red   = part + (size_t)8 * 64 * 2048;         // 250*64*8

  unsigned short* us = (unsigned short*)(red + 250 * 64 * 8);
  unsigned short* embbf  = us;                                  // 32000*512
  unsigned short* imghi  = embbf + (size_t)VOC * EMBN;          // 3136*2048
  unsigned short* imglo  = imghi + (size_t)3136 * 2048;
  unsigned short* wfh_hi = imglo + (size_t)3136 * 2048;         // 512*2048 (W_fh^T)
  unsigned short* wfh_lo = wfh_hi + (size_t)512 * 2048;
  unsigned short* wg     = wfh_lo + (size_t)512 * 2048;         // [l][mat][hi/lo][2048][512]
  const size_t WGM = (size_t)2048 * 512;
  unsigned short* xhi    = wg + 8 * WGM;                        // 64*512
  unsigned short* xlo    = xhi + 64 * 512;
  unsigned short* hshi   = xlo + 64 * 512;                      // 2*64*512
  unsigned short* hslo   = hshi + 2 * 64 * 512;                 // 2*64*512

  auto wgp = [&](int l, int mat, int part_) -> unsigned short* {
    return wg + (((size_t)l * 2 + mat) * 2 + part_) * WGM;
  };

  // ---- one-time prep ----
  k_emb2bf<<<8000, 256, 0, stream>>>(emb, embbf);
  k_split<<<3136 * 2048 / 8 / 256, 256, 0, stream>>>(img, imghi, imglo);
  k_trans<<<dim3(FEATN / 32, FHN / 32), 256, 0, stream>>>(W_fh, wfh_hi, wfh_lo, FEATN, FHN);
  for (int l = 0; l < 2; ++l) {
    k_trans<<<dim3(EMBN / 32, G4 / 32), 256, 0, stream>>>(W_ih + (size_t)l * EMBN * G4, wgp(l, 0, 0), wgp(l, 0, 1), EMBN, G4);
    k_trans<<<dim3(HID / 32, G4 / 32), 256, 0, stream>>>(W_hh + (size_t)l * HID * G4, wgp(l, 1, 0), wgp(l, 1, 1), HID, G4);
  }
  k_feat_mfma<<<dim3(49, 8), 256, 0, stream>>>(imghi, imglo, wfh_hi, wfh_lo, b_fh, femb);
  k_mean<<<128, 256, 0, stream>>>(femb, fmean);
  k_h0c0<<<dim3(8, 2, 2), 256, 0, stream>>>(fmean, Wc, bc, Wh, bh, hbuf, cbuf, hshi, hslo);
  k_initx<<<128, 256, 0, stream>>>(xhi, xlo);

  for (int t = 0; t < TSTEPS; ++t) {
    const float* gum_t = gum + (size_t)t * BATCH * VOC;
    // layer 0: x=xbuf, h=h0
    k_gates_mfma<<<dim3(32, 8), 256, 0, stream>>>(xhi, xlo, hshi, hslo,
        wgp(0, 0, 0), wgp(0, 0, 1), wgp(0, 1, 0), wgp(0, 1, 1), part);
    k_cell<<<128, 256, 0, stream>>>(part, b_l, hbuf, cbuf, hshi, hslo);
    // layer 1: x=h0new, h=h1
    k_gates_mfma<<<dim3(32, 8), 256, 0, stream>>>(hshi, hslo, hshi + 64 * 512, hslo + 64 * 512,
        wgp(1, 0, 0), wgp(1, 0, 1), wgp(1, 1, 0), wgp(1, 1, 1), part);
    k_cell<<<128, 256, 0, stream>>>(part, b_l + 2048, hbuf + 64 * 512, cbuf + 64 * 512,
                                    hshi + 64 * 512, hslo + 64 * 512);
    // vocab projection (bf16 MFMA) + LSE partials + top-2 screening
    k_logits_mfma<<<NVT, 256, 0, stream>>>(embbf, hshi + 64 * 512, gum_t, red);
    // final reduce + exact rescore + sample (+ next-x split emit)
    k_sample<<<64, 256, 0, stream>>>(red, emb, hbuf + 64 * 512, gum_t, xhi, xlo, out, t);
  }
}